// Round 4
// baseline (772.625 us; speedup 1.0000x reference)
//
#include <hip/hip_runtime.h>
#include <cmath>
#include <stdint.h>

#define B_ 32
#define T_ 2048
#define H_ 1024

typedef __attribute__((ext_vector_type(8))) __bf16 bf16x8;
typedef __attribute__((ext_vector_type(4))) float f32x4;

__device__ inline void async_copy16(const void* g, void* l) {
    __builtin_amdgcn_global_load_lds((const __attribute__((address_space(1))) uint32_t*)g,
                                     (__attribute__((address_space(3))) uint32_t*)l, 16, 0, 0);
}

__device__ inline float fast_tanh(float x) {
    float e = __expf(2.f * x);
    return 1.f - 2.f / (e + 1.f);
}

__global__ __launch_bounds__(256) void zero_kernel(float* __restrict__ p, int n) {
    int i = blockIdx.x * 256 + threadIdx.x;
    if (i < n) p[i] = 0.f;
}

// fp32 -> bf16, 8 elements/thread
__global__ __launch_bounds__(256) void convert_kernel(const float* __restrict__ in,
                                                      __bf16* __restrict__ out) {
    size_t i = (size_t)(blockIdx.x * 256 + threadIdx.x) * 8;
    const float4* p = (const float4*)(in + i);
    float4 v0 = p[0], v1 = p[1];
    bf16x8 o;
    o[0] = (__bf16)v0.x; o[1] = (__bf16)v0.y; o[2] = (__bf16)v0.z; o[3] = (__bf16)v0.w;
    o[4] = (__bf16)v1.x; o[5] = (__bf16)v1.y; o[6] = (__bf16)v1.z; o[7] = (__bf16)v1.w;
    *(bf16x8*)(out + i) = o;
}

// kq[b,h] = Wq[h,:]·dec[b,:] + bq[h] + bk[h]
__global__ __launch_bounds__(256) void q_kernel(const float* __restrict__ dec,
                                                const float* __restrict__ Wq,
                                                const float* __restrict__ bq,
                                                const float* __restrict__ bk,
                                                float* __restrict__ kq) {
    int b = blockIdx.x;
    int hc = blockIdx.y;
    __shared__ float ds[H_];
    for (int i = threadIdx.x; i < H_; i += 256) ds[i] = dec[b * H_ + i];
    __syncthreads();
    int h = hc * 256 + threadIdx.x;
    const float4* w = (const float4*)(Wq + (size_t)h * H_);
    float acc = 0.f;
#pragma unroll 8
    for (int j = 0; j < H_ / 4; j++) {
        float4 v = w[j];
        acc += v.x * ds[4 * j] + v.y * ds[4 * j + 1] + v.z * ds[4 * j + 2] + v.w * ds[4 * j + 3];
    }
    kq[b * H_ + h] = acc + bq[h] + bk[h];
}

// MFMA score GEMM, 128x128 tile, BK=64, XCD-affine swizzle, partial-score stores.
// 16 partial slices: slice = g*2 + wn; each wave stores its 64-column partial.
// sp[slice][m] = sum_{h in wave's 64 cols} Wout[h]*tanh(enc[m,:]·Wk[h,:] + kq[b,h])
__global__ __launch_bounds__(256) void score_mfma(const __bf16* __restrict__ encb,
                                                  const __bf16* __restrict__ Wkb,
                                                  const float* __restrict__ kq,
                                                  const float* __restrict__ Wout,
                                                  float* __restrict__ sp) {
    __shared__ __align__(16) __bf16 As[1024 * 8];  // 16 KB: 8 kgroups x 128 rows x 8 bf16
    __shared__ __align__(16) __bf16 Bs[1024 * 8];  // 16 KB

    // swizzle: all 8 h-tiles of an m-tile share bid%8 -> same XCD (round-robin heuristic)
    const int bid = blockIdx.x;
    const int xcd = bid & 7;
    const int g = (bid >> 3) & 7;        // h-tile 0..7
    const int mt = (bid >> 6) * 8 + xcd; // m-tile 0..511
    const int h0 = g * 128;
    const int m0 = mt * 128;
    const int b = m0 >> 11;
    const int tid = threadIdx.x;
    const int lane = tid & 63;
    const int w = tid >> 6;
    const int wm = w & 1, wn = w >> 1;
    const int q4 = lane >> 4, l15 = lane & 15;

    // staging: 4 slots per matrix per thread; slot S -> chunk [kg=S>>7][row=S&127]
    int kgs[4], rows[4];
    const __bf16 *gA[4], *gB[4];
    __bf16 *lA[4], *lB[4];
#pragma unroll
    for (int r = 0; r < 4; r++) {
        int S = w * 256 + r * 64 + lane;
        kgs[r] = S >> 7;
        rows[r] = S & 127;
        gA[r] = encb + (size_t)(m0 + rows[r]) * H_ + kgs[r] * 8;
        gB[r] = Wkb + (size_t)(h0 + rows[r]) * H_ + kgs[r] * 8;
        lA[r] = As + (size_t)(w * 256 + r * 64) * 8;  // wave-uniform base; HW adds lane*16B
        lB[r] = Bs + (size_t)(w * 256 + r * 64) * 8;
    }

    f32x4 acc[4][4];
#pragma unroll
    for (int i = 0; i < 4; i++)
#pragma unroll
        for (int j = 0; j < 4; j++) acc[i][j] = (f32x4){0.f, 0.f, 0.f, 0.f};

    for (int k0 = 0; k0 < H_; k0 += 64) {
        __syncthreads();
#pragma unroll
        for (int r = 0; r < 4; r++) async_copy16(gA[r] + k0, lA[r]);
#pragma unroll
        for (int r = 0; r < 4; r++) async_copy16(gB[r] + k0, lB[r]);
        __syncthreads();

#pragma unroll
        for (int kb = 0; kb < 2; kb++) {  // two 32-k steps within the 64-k stage
            bf16x8 a[4], bb[4];
#pragma unroll
            for (int mf = 0; mf < 4; mf++)
                a[mf] = *(const bf16x8*)(As + (size_t)(((kb * 4 + q4) * 128) + wm * 64 + mf * 16 + l15) * 8);
#pragma unroll
            for (int nf = 0; nf < 4; nf++)
                bb[nf] = *(const bf16x8*)(Bs + (size_t)(((kb * 4 + q4) * 128) + wn * 64 + nf * 16 + l15) * 8);
#pragma unroll
            for (int mf = 0; mf < 4; mf++)
#pragma unroll
                for (int nf = 0; nf < 4; nf++)
                    acc[mf][nf] = __builtin_amdgcn_mfma_f32_16x16x32_bf16(a[mf], bb[nf], acc[mf][nf], 0, 0, 0);
        }
    }

    float wv[4], kqv[4];
#pragma unroll
    for (int nf = 0; nf < 4; nf++) {
        int h = h0 + wn * 64 + nf * 16 + l15;
        wv[nf] = Wout[h];
        kqv[nf] = kq[b * H_ + h];
    }
    const size_t slice = (size_t)(g * 2 + wn) * (B_ * T_);
#pragma unroll
    for (int mf = 0; mf < 4; mf++) {
#pragma unroll
        for (int r = 0; r < 4; r++) {
            float s = 0.f;
#pragma unroll
            for (int nf = 0; nf < 4; nf++)
                s += wv[nf] * fast_tanh(acc[mf][nf][r] + kqv[nf]);
#pragma unroll
            for (int m = 1; m < 16; m <<= 1) s += __shfl_xor(s, m, 64);
            if (l15 == 0)
                sp[slice + m0 + wm * 64 + mf * 16 + q4 * 4 + r] = s;
        }
    }
}

// softmax over T per b; input = 16 partial slices, output attn
__global__ __launch_bounds__(256) void softmax_kernel(const float* __restrict__ sp,
                                                      float* __restrict__ attn) {
    int b = blockIdx.x, tid = threadIdx.x;
    __shared__ float red[8];
    float v[8];
    float mx = -1e30f;
#pragma unroll
    for (int i = 0; i < 8; i++) {
        int t = tid + i * 256;
        float s = 0.f;
#pragma unroll
        for (int sl = 0; sl < 16; sl++) s += sp[(size_t)sl * (B_ * T_) + b * T_ + t];
        v[i] = s;
        mx = fmaxf(mx, s);
    }
#pragma unroll
    for (int m = 32; m >= 1; m >>= 1) mx = fmaxf(mx, __shfl_xor(mx, m, 64));
    if ((tid & 63) == 0) red[tid >> 6] = mx;
    __syncthreads();
    mx = fmaxf(fmaxf(red[0], red[1]), fmaxf(red[2], red[3]));
    float sum = 0.f;
#pragma unroll
    for (int i = 0; i < 8; i++) {
        v[i] = __expf(v[i] - mx);
        sum += v[i];
    }
#pragma unroll
    for (int m = 32; m >= 1; m >>= 1) sum += __shfl_xor(sum, m, 64);
    if ((tid & 63) == 0) red[4 + (tid >> 6)] = sum;
    __syncthreads();
    sum = red[4] + red[5] + red[6] + red[7];
    float inv = 1.f / sum;
#pragma unroll
    for (int i = 0; i < 8; i++) attn[b * T_ + tid + i * 256] = v[i] * inv;
}

// context stage 1: cpart[b][ts][h] = sum_{t in 64-token slice ts} attn[b,t]*enc[b,t,h]
__global__ __launch_bounds__(256) void context_part(const float* __restrict__ enc,
                                                    const float* __restrict__ attn,
                                                    float* __restrict__ cpart) {
    int ts = blockIdx.x, b = blockIdx.y;
    const float* e = enc + (size_t)b * T_ * H_ + (size_t)ts * 64 * H_ + threadIdx.x * 4;
    const float* a = attn + b * T_ + ts * 64;
    float4 acc = {0.f, 0.f, 0.f, 0.f};
#pragma unroll 4
    for (int t = 0; t < 64; t++) {
        float av = a[t];
        float4 v = *(const float4*)(e + (size_t)t * H_);
        acc.x += av * v.x; acc.y += av * v.y; acc.z += av * v.z; acc.w += av * v.w;
    }
    *(float4*)(cpart + ((size_t)b * 32 + ts) * H_ + threadIdx.x * 4) = acc;
}

// context stage 2: out[b,h] = sum_ts cpart[b][ts][h]
__global__ __launch_bounds__(256) void context_reduce(const float* __restrict__ cpart,
                                                      float* __restrict__ out) {
    int hc = blockIdx.x, b = blockIdx.y;
    int h = hc * 256 + threadIdx.x;
    float s = 0.f;
#pragma unroll
    for (int ts = 0; ts < 32; ts++) s += cpart[((size_t)b * 32 + ts) * H_ + h];
    out[b * H_ + h] = s;
}

// ---------- fp32 fallback score + atomic context (used only if ws too small) ----------
#define BK 32
#define ASTR 68
#define BSTR 132
__global__ __launch_bounds__(256) void score_fp32(const float* __restrict__ enc,
                                                  const float* __restrict__ Wk,
                                                  const float* __restrict__ kq,
                                                  const float* __restrict__ Wout,
                                                  float* __restrict__ score) {
    __shared__ __align__(16) float As2[BK * ASTR];
    __shared__ __align__(16) float Bs2[BK * BSTR];
    __shared__ float wout_s[128];
    __shared__ float kq_s[128];
    const int m0 = blockIdx.x * 64;
    const int h0 = blockIdx.y * 128;
    const int b = m0 >> 11;
    const int tid = threadIdx.x;
    const int tx = tid & 15;
    const int ty = tid >> 4;
    if (tid < 128) {
        wout_s[tid] = Wout[h0 + tid];
        kq_s[tid] = kq[b * H_ + h0 + tid];
    }
    float acc[4][8];
#pragma unroll
    for (int i = 0; i < 4; i++)
#pragma unroll
        for (int j = 0; j < 8; j++) acc[i][j] = 0.f;
    for (int k0 = 0; k0 < H_; k0 += BK) {
        __syncthreads();
#pragma unroll
        for (int r = 0; r < 2; r++) {
            int li = tid + r * 256;
            int tok = li >> 3, kg = li & 7;
            float4 v = *(const float4*)(enc + (size_t)(m0 + tok) * H_ + k0 + kg * 4);
            As2[(kg * 4 + 0) * ASTR + tok] = v.x;
            As2[(kg * 4 + 1) * ASTR + tok] = v.y;
            As2[(kg * 4 + 2) * ASTR + tok] = v.z;
            As2[(kg * 4 + 3) * ASTR + tok] = v.w;
        }
#pragma unroll
        for (int r = 0; r < 4; r++) {
            int li = tid + r * 256;
            int h = li >> 3, kg = li & 7;
            float4 v = *(const float4*)(Wk + (size_t)(h0 + h) * H_ + k0 + kg * 4);
            Bs2[(kg * 4 + 0) * BSTR + h] = v.x;
            Bs2[(kg * 4 + 1) * BSTR + h] = v.y;
            Bs2[(kg * 4 + 2) * BSTR + h] = v.z;
            Bs2[(kg * 4 + 3) * BSTR + h] = v.w;
        }
        __syncthreads();
#pragma unroll
        for (int kk = 0; kk < BK; kk++) {
            float4 a4 = *(const float4*)&As2[kk * ASTR + ty * 4];
            float4 b4a = *(const float4*)&Bs2[kk * BSTR + tx * 4];
            float4 b4b = *(const float4*)&Bs2[kk * BSTR + 64 + tx * 4];
            float av[4] = {a4.x, a4.y, a4.z, a4.w};
            float bv[8] = {b4a.x, b4a.y, b4a.z, b4a.w, b4b.x, b4b.y, b4b.z, b4b.w};
#pragma unroll
            for (int i = 0; i < 4; i++)
#pragma unroll
                for (int j = 0; j < 8; j++) acc[i][j] += av[i] * bv[j];
        }
    }
    float wv[8], kqv[8];
#pragma unroll
    for (int j = 0; j < 8; j++) {
        int hl = (j < 4) ? (tx * 4 + j) : (64 + tx * 4 + (j - 4));
        wv[j] = wout_s[hl];
        kqv[j] = kq_s[hl];
    }
#pragma unroll
    for (int i = 0; i < 4; i++) {
        float s = 0.f;
#pragma unroll
        for (int j = 0; j < 8; j++) s += wv[j] * tanhf(acc[i][j] + kqv[j]);
#pragma unroll
        for (int m = 1; m < 16; m <<= 1) s += __shfl_xor(s, m, 64);
        if (tx == 0) atomicAdd(&score[m0 + ty * 4 + i], s);
    }
}

__global__ __launch_bounds__(256) void softmax_inplace(float* __restrict__ score) {
    int b = blockIdx.x, tid = threadIdx.x;
    float* s = score + b * T_;
    __shared__ float red[8];
    float v[8];
    float mx = -1e30f;
#pragma unroll
    for (int i = 0; i < 8; i++) {
        v[i] = s[tid + i * 256];
        mx = fmaxf(mx, v[i]);
    }
#pragma unroll
    for (int m = 32; m >= 1; m >>= 1) mx = fmaxf(mx, __shfl_xor(mx, m, 64));
    if ((tid & 63) == 0) red[tid >> 6] = mx;
    __syncthreads();
    mx = fmaxf(fmaxf(red[0], red[1]), fmaxf(red[2], red[3]));
    float sum = 0.f;
#pragma unroll
    for (int i = 0; i < 8; i++) {
        v[i] = __expf(v[i] - mx);
        sum += v[i];
    }
#pragma unroll
    for (int m = 32; m >= 1; m >>= 1) sum += __shfl_xor(sum, m, 64);
    if ((tid & 63) == 0) red[4 + (tid >> 6)] = sum;
    __syncthreads();
    sum = red[4] + red[5] + red[6] + red[7];
    float inv = 1.f / sum;
#pragma unroll
    for (int i = 0; i < 8; i++) s[tid + i * 256] = v[i] * inv;
}
// --------------------------------------------------------------------------

extern "C" void kernel_launch(void* const* d_in, const int* in_sizes, int n_in,
                              void* d_out, int out_size, void* d_ws, size_t ws_size,
                              hipStream_t stream) {
    const float* enc = (const float*)d_in[0];
    const float* dec = (const float*)d_in[1];
    const float* Wk = (const float*)d_in[2];
    const float* bk = (const float*)d_in[3];
    const float* Wq = (const float*)d_in[4];
    const float* bq = (const float*)d_in[5];
    const float* Wout = (const float*)d_in[6];
    // d_in[7] = bout: cancels under softmax. d_in[8] = inputs: unused.
    float* out = (float*)d_out;

    const size_t encb_bytes = (size_t)B_ * T_ * H_ * 2;            // 134217728
    const size_t wkb_bytes = (size_t)H_ * H_ * 2;                  // 2097152
    const size_t kq_bytes = (size_t)B_ * H_ * 4;                   // 131072
    const size_t attn_bytes = (size_t)B_ * T_ * 4;                 // 262144
    const size_t sp_bytes = (size_t)16 * B_ * T_ * 4;              // 4194304
    const size_t cpart_bytes = (size_t)B_ * 32 * H_ * 4;           // 4194304
    const size_t shared_bytes = sp_bytes > cpart_bytes ? sp_bytes : cpart_bytes;
    const size_t need = encb_bytes + wkb_bytes + kq_bytes + attn_bytes + shared_bytes;

    if (ws_size >= need) {
        char* p = (char*)d_ws;
        __bf16* encb = (__bf16*)p;            p += encb_bytes;
        __bf16* Wkb = (__bf16*)p;             p += wkb_bytes;
        float* kq = (float*)p;                p += kq_bytes;
        float* attn = (float*)p;              p += attn_bytes;
        float* sp = (float*)p;                // overlaps cpart (disjoint lifetimes)
        float* cpart = (float*)p;

        convert_kernel<<<(B_ * T_ * H_) / 2048, 256, 0, stream>>>(enc, encb);
        convert_kernel<<<(H_ * H_) / 2048, 256, 0, stream>>>(Wk, Wkb);
        q_kernel<<<dim3(B_, 4), 256, 0, stream>>>(dec, Wq, bq, bk, kq);
        score_mfma<<<4096, 256, 0, stream>>>(encb, Wkb, kq, Wout, sp);
        softmax_kernel<<<B_, 256, 0, stream>>>(sp, attn);
        context_part<<<dim3(32, B_), 256, 0, stream>>>(enc, attn, cpart);
        context_reduce<<<dim3(4, B_), 256, 0, stream>>>(cpart, out);
    } else {
        float* kq = (float*)d_ws;
        float* score = kq + B_ * H_;
        float* cpart = score + B_ * T_;
        q_kernel<<<dim3(B_, 4), 256, 0, stream>>>(dec, Wq, bq, bk, kq);
        zero_kernel<<<(B_ * T_ + 255) / 256, 256, 0, stream>>>(score, B_ * T_);
        score_fp32<<<dim3(1024, 8), 256, 0, stream>>>(enc, Wk, kq, Wout, score);
        softmax_inplace<<<B_, 256, 0, stream>>>(score);
        context_part<<<dim3(32, B_), 256, 0, stream>>>(enc, score, cpart);
        context_reduce<<<dim3(4, B_), 256, 0, stream>>>(cpart, out);
    }
}